// Round 6
// baseline (436.330 us; speedup 1.0000x reference)
//
#include <hip/hip_runtime.h>
#include <hip/hip_bf16.h>

typedef float f32x4 __attribute__((ext_vector_type(4)));
typedef unsigned int u32;
typedef short short8 __attribute__((ext_vector_type(8)));

#define BATCH 8
#define CH    128
#define HWN   50176
#define PN    128
#define KSPLIT 64
#define KWIN  784          // HWN / KSPLIT
#define BK    112          // fp32 k-cols per stage (448 B per row)
#define NST   7            // KWIN / BK exact

__device__ __forceinline__ ushort f2bf_rn(float f){
  u32 u = __float_as_uint(f);
  u += 0x7FFFu + ((u >> 16) & 1u);
  return (ushort)(u >> 16);
}

// mask values are exactly 0.0f/1.0f -> truncation exact
__device__ __forceinline__ short8 cvt8_trunc(f32x4 a, f32x4 b){
  union{ short8 v; ushort u[8]; } r;
  r.u[0]=(ushort)(__float_as_uint(a.x)>>16); r.u[1]=(ushort)(__float_as_uint(a.y)>>16);
  r.u[2]=(ushort)(__float_as_uint(a.z)>>16); r.u[3]=(ushort)(__float_as_uint(a.w)>>16);
  r.u[4]=(ushort)(__float_as_uint(b.x)>>16); r.u[5]=(ushort)(__float_as_uint(b.y)>>16);
  r.u[6]=(ushort)(__float_as_uint(b.z)>>16); r.u[7]=(ushort)(__float_as_uint(b.w)>>16);
  return r.v;
}

// hi = truncate-to-bf16, lo = rn(f - hi)
__device__ __forceinline__ void cvt8_hilo(f32x4 a, f32x4 b, short8& h8, short8& l8){
  union{ short8 v; ushort u[8]; } h, l;
  float f[8] = {a.x,a.y,a.z,a.w,b.x,b.y,b.z,b.w};
  #pragma unroll
  for(int j=0;j<8;++j){
    u32 uu = __float_as_uint(f[j]);
    ushort hh = (ushort)(uu >> 16);
    h.u[j] = hh;
    l.u[j] = f2bf_rn(f[j] - __uint_as_float((u32)hh << 16));
  }
  h8 = h.v; l8 = l.v;
}

// ---------------------------------------------------------------------------
// 512 blocks = (b, s in [0,64)) : 128x128 partial over k-window of 784.
// 512 thr / 8 waves; 2 blocks/CU (16 waves/CU) — the single-variable change.
// Wave w owns c-rows [w*16, w*16+16) x all 128 p.
// X: per-lane register stream (R4 pattern), 4-deep k-step ring.
// M: reg-staged 128B bursts -> bf16 -> swizzled LDS [2][128][256B] dbuf.
// Stage = 112 floats = 3 full k32 steps + 1 zero-padded k32 step.
// Raw s_barrier + lgkmcnt only — X/M prefetches survive barriers.
// ---------------------------------------------------------------------------
template<int EPI>
__global__ __launch_bounds__(512, 4)
void raggr_kernel(const float* __restrict__ X, const float* __restrict__ Mk,
                  float* __restrict__ OUT, float* __restrict__ PART){
  __shared__ char mlds[2 * 32768];   // [buf][128 rows][256 B pitch], 64 KB

  const int tid  = threadIdx.x;
  const int b    = blockIdx.x >> 6;
  const int s    = blockIdx.x & 63;
  const int lane = tid & 63;
  const int w    = tid >> 6;          // 0..7
  const int l15  = lane & 15;
  const int hi4  = lane >> 4;         // 0..3

  const size_t base = (size_t)b * CH * HWN + (size_t)s * KWIN;
  const f32x4 z4 = {0.f,0.f,0.f,0.f};

  // X stream: lane owns c-row (w*16 + l15)
  const int arow = w*16 + l15;
  const float* pXb = X + base + (size_t)arow * HWN;
  const int xo  = hi4 * 8;                    // k32-step lane offset
  const int xo3 = (hi4 < 2) ? hi4*8 : 8;      // padded step (clamped dup)

  // M staging: row mr = tid>>2, chunk mc = tid&3 (mc<3: 32 floats, mc==3: 16)
  const int mr = tid >> 2;
  const int mc = tid & 3;
  const float* pMs = Mk + base + (size_t)mr * HWN + mc*32;
  const int r7 = mr & 7;

  f32x4 xr[4][2];    // 4-deep k-step ring (static indices via full unroll)
  f32x4 mreg[8];
  f32x4 acc[8];
  #pragma unroll
  for(int n=0;n<8;++n) acc[n] = z4;

  #define XISSUE(g) {                                                         \
    const int t_=(g)>>2, j_=(g)&3;                                            \
    const size_t o_ = (size_t)(t_*112 + (j_<3 ? j_*32 + xo : 96 + xo3));      \
    xr[(g)&3][0] = *(const f32x4*)(pXb + o_);                                 \
    xr[(g)&3][1] = *(const f32x4*)(pXb + o_ + 4); }

  #define MISSUE(t) { _Pragma("unroll")                                       \
    for(int i=0;i<8;++i){                                                     \
      if(i<4 || mc<3)                                                         \
        mreg[i] = *(const f32x4*)(pMs + (size_t)(t)*BK + i*4); } }

  #define CVTW(t) {                                                           \
    char* dst = mlds + ((t)&1)*32768 + mr*256;                                \
    _Pragma("unroll")                                                         \
    for(int u=0;u<4;++u){                                                     \
      if(u<2 || mc<3){                                                        \
        short8 v = cvt8_trunc(mreg[2*u], mreg[2*u+1]);                        \
        *(short8*)(dst + ((((mc<<2)+u) ^ r7) << 4)) = v;                      \
      } } }

  // prologue
  XISSUE(0); XISSUE(1); XISSUE(2); XISSUE(3);
  MISSUE(0);
  CVTW(0);
  MISSUE(1);
  asm volatile("s_waitcnt lgkmcnt(0)" ::: "memory");
  __builtin_amdgcn_s_barrier();
  __builtin_amdgcn_sched_barrier(0);

  #pragma unroll
  for(int g=0; g<NST*4; ++g){
    const int t_ = g >> 2;
    const int j_ = g & 3;
    const char* Mb = mlds + (t_ & 1)*32768;

    // A frag from streamed regs (zero-pad lanes hi4>=2 on the 4th step)
    f32x4 v0 = xr[g&3][0], v1 = xr[g&3][1];
    if(j_ == 3 && hi4 >= 2){ v0 = z4; v1 = z4; }
    short8 ah, al;
    cvt8_hilo(v0, v1, ah, al);

    // B frags from LDS (unit: j<3 -> j*4+hi4; j==3 -> 12+min(hi4,1); garbage
    // dup for hi4>=2 is safe since A is zero there)
    const int unit = (j_ < 3) ? (j_*4 + hi4) : (12 + ((hi4 < 2) ? hi4 : 1));
    #pragma unroll
    for(int n=0;n<8;++n){
      const int p = n*16 + l15;
      short8 bf = *(const short8*)(Mb + p*256 + ((unit ^ (p & 7)) << 4));
      acc[n] = __builtin_amdgcn_mfma_f32_16x16x32_bf16(ah, bf, acc[n], 0,0,0);
      acc[n] = __builtin_amdgcn_mfma_f32_16x16x32_bf16(al, bf, acc[n], 0,0,0);
    }

    if(g + 4 < NST*4) XISSUE(g + 4);

    if(j_ == 3 && t_ < NST-1){          // stage boundary
      CVTW(t_ + 1);                     // waits mreg loads (counted vmcnt)
      if(t_ < NST-2) MISSUE(t_ + 2);
      asm volatile("s_waitcnt lgkmcnt(0)" ::: "memory");
      __builtin_amdgcn_s_barrier();
      __builtin_amdgcn_sched_barrier(0);
    }
  }

  // epilogue — C/D layout: col=lane&15, row=(lane>>4)*4+j  [m89]
  if(EPI == 0){
    // PART layout [b][c][s][p] : b*1048576 + row*8192 + s*128 + col
    #pragma unroll
    for(int n=0;n<8;++n){
      int col  = n*16 + l15;
      int row0 = w*16 + hi4*4;
      #pragma unroll
      for(int j=0;j<4;++j)
        PART[(size_t)b*1048576 + (size_t)(row0+j)*8192 + s*128 + col] = acc[n][j];
    }
  } else {
    float* o = OUT + (size_t)b * 16384;
    #pragma unroll
    for(int n=0;n<8;++n){
      int col  = n*16 + l15;
      int row0 = w*16 + hi4*4;
      #pragma unroll
      for(int j=0;j<4;++j) atomicAdd(&o[(size_t)(row0+j)*128 + col], acc[n][j]);
    }
  }
  #undef XISSUE
  #undef MISSUE
  #undef CVTW
}

// out[b][c][p] = sum_s PART[b][c][s][p] — coalesced across p.
__global__ void reduce_kernel(const float* __restrict__ PART, float* __restrict__ OUT){
  int idx = blockIdx.x * 256 + threadIdx.x;   // 0 .. 131071
  int p = idx & 127;
  int c = (idx >> 7) & 127;
  int b = idx >> 14;
  size_t base_ = (size_t)b*1048576 + (size_t)c*8192 + p;
  float sum = 0.f;
  #pragma unroll 8
  for(int s2=0; s2<KSPLIT; ++s2) sum += PART[base_ + (size_t)s2*128];
  OUT[idx] = sum;
}

__global__ void zero_kernel(float* __restrict__ OUT){
  int idx = blockIdx.x * 256 + threadIdx.x;
  if(idx < BATCH*CH*PN) OUT[idx] = 0.f;
}

extern "C" void kernel_launch(void* const* d_in, const int* in_sizes, int n_in,
                              void* d_out, int out_size, void* d_ws, size_t ws_size,
                              hipStream_t stream){
  const float* X  = (const float*)d_in[0];
  const float* Mk = (const float*)d_in[1];
  float* O = (float*)d_out;

  const size_t part_bytes = (size_t)BATCH * KSPLIT * CH * PN * sizeof(float); // 33.5 MB
  if(ws_size >= part_bytes && d_ws != nullptr){
    float* part = (float*)d_ws;
    raggr_kernel<0><<<dim3(BATCH*KSPLIT), dim3(512), 0, stream>>>(X, Mk, O, part);
    reduce_kernel<<<dim3(512), dim3(256), 0, stream>>>(part, O);
  } else {
    zero_kernel<<<dim3(512), dim3(256), 0, stream>>>(O);
    raggr_kernel<1><<<dim3(BATCH*KSPLIT), dim3(512), 0, stream>>>(X, Mk, O, nullptr);
  }
}